// Round 6
// baseline (2646.022 us; speedup 1.0000x reference)
//
#include <hip/hip_runtime.h>

// Gemma3 forward, MI355X. Round 6: round-5 structure + fix for sliding-band
// QK with BM=64 (floor tile origin to 128-alignment so the left edge of the
// window band is always computed).
// L=18 H=640 NH=4 NKV=1 HD=256 I=2048 V=32768 B=1 S=1024 WINDOW=512

typedef unsigned short u16;
typedef __attribute__((ext_vector_type(4))) float f32x4;
typedef __attribute__((ext_vector_type(8))) short bf16x8;

#define DEV static __device__ __forceinline__

DEV u16 f2bf(float f) {  // round-to-nearest-even fp32 -> bf16
  union { float f; unsigned u; } x; x.f = f;
  unsigned r = x.u + 0x7fffu + ((x.u >> 16) & 1u);
  return (u16)(r >> 16);
}

#define GLOAD16(gp, lp) __builtin_amdgcn_global_load_lds( \
    (const __attribute__((address_space(1))) void*)(gp), \
    (__attribute__((address_space(3))) void*)(lp), 16, 0, 0)

DEV float blockSum(float v, float* red) {
#pragma unroll
  for (int o = 32; o; o >>= 1) v += __shfl_down(v, o);
  int lane = threadIdx.x & 63, wid = threadIdx.x >> 6;
  if (lane == 0) red[wid] = v;
  __syncthreads();
  float s = red[0] + red[1] + red[2] + red[3];
  __syncthreads();
  return s;
}

DEV void cstore(float* C, size_t i, float v) { C[i] = v; }
DEV void cstore(u16* C, size_t i, float v) { C[i] = f2bf(v); }

// ---- GEMM NT: C[M,N] = alpha * A[M,K]bf16 * (B[N,K]bf16)^T ----
// BMxBN(128) tile, BK=64, double-buffered LDS, depth-1 prefetch, XOR-swizzled
// LDS (pre-swizzled global source, linear global_load_lds dest).
// nshift: -1 plain; -2 causal tile-skip; >=0 sliding band,
//   n0 = floor128(m0 - nshift) + bx*128  (128-aligned so band left edge is
//   covered even when BM=64 makes m0 = 64 mod 128), skip n0<0.
// kmode: 0 full K; 2 causal K-band; 3 split-K over blockIdx.z.
// Stores guarded by col<nmax.
template <typename CT, int GEGLU, int BM>
__global__ __launch_bounds__(256) void gemm_nt(
    const u16* __restrict__ A, int lda, long sA,
    const u16* __restrict__ B, int ldb, long sB,
    CT* __restrict__ C, int ldc, long sC,
    int K, float alpha, int kmode, int nshift, int ksplit, int nmax) {
  constexpr int MI = BM / 32;
  __shared__ __align__(16) u16 As[2 * BM * 64];
  __shared__ __align__(16) u16 Bs[2 * 128 * 64];
  const int m0 = blockIdx.y * BM;
  int n0;
  if (nshift == -1) n0 = blockIdx.x * 128;
  else if (nshift == -2) { n0 = blockIdx.x * 128; if (n0 > m0) return; }
  else { n0 = ((m0 - nshift) & ~127) + blockIdx.x * 128; if (n0 < 0) return; }
  int klo = 0, khi = K;
  if (kmode == 2) { khi = m0 + BM; if (khi > K) khi = K; }
  else if (kmode == 3) { int kl = K / ksplit; klo = blockIdx.z * kl; khi = klo + kl; }
  A += (long)blockIdx.z * sA;
  B += (long)blockIdx.z * sB;

  const int t = threadIdx.x;
  const int l = t & 63, w = t >> 6;
  const int wr = w >> 1, wc = w & 1;        // 2x2 waves
  const int lr = l & 15, lk = l >> 4;
  const int axr = lr & 7;                   // ds_read swizzle key
  const int srow = t >> 3;                  // staging row 0..31 (+32p)
  const int scolx = ((t & 7) ^ (srow & 7)) << 3;  // pre-swizzled global col
  const u16* Ag = A + (size_t)(m0 + srow) * lda + scolx;
  const u16* Bg = B + (size_t)(n0 + srow) * ldb + scolx;
  const int nsteps = (khi - klo) >> 6;

  auto stage = [&](int db, int k0) {
    u16* al = As + db * (BM * 64) + w * 512;  // wave-uniform LDS bases
    u16* bl = Bs + db * 8192 + w * 512;
#pragma unroll
    for (int p = 0; p < BM / 32; ++p)
      GLOAD16(Ag + k0 + (size_t)(32 * p) * lda, al + p * 2048);
#pragma unroll
    for (int p = 0; p < 4; ++p)
      GLOAD16(Bg + k0 + (size_t)(32 * p) * ldb, bl + p * 2048);
  };

  stage(0, klo);
  f32x4 acc[MI][4] = {};

  for (int s = 0; s < nsteps; ++s) {
    __syncthreads();                        // drains prefetch; joins prior ds_reads
    const int db = s & 1;
    if (s + 1 < nsteps) stage(db ^ 1, klo + (s + 1) * 64);
    const u16* Ab = As + db * (BM * 64);
    const u16* Bb = Bs + db * 8192;
    bf16x8 af[2][MI], bfr[2][4];
#pragma unroll
    for (int kk = 0; kk < 2; ++kk) {
#pragma unroll
      for (int i = 0; i < MI; ++i)
        af[kk][i] = *(const bf16x8*)&Ab[(wr * (BM / 2) + i * 16 + lr) * 64 + (((kk * 4 + lk) ^ axr) << 3)];
#pragma unroll
      for (int i = 0; i < 4; ++i)
        bfr[kk][i] = *(const bf16x8*)&Bb[(wc * 64 + i * 16 + lr) * 64 + (((kk * 4 + lk) ^ axr) << 3)];
    }
#pragma unroll
    for (int kk = 0; kk < 2; ++kk)
#pragma unroll
      for (int mi = 0; mi < MI; ++mi)
#pragma unroll
        for (int ni = 0; ni < 4; ++ni)
          acc[mi][ni] = __builtin_amdgcn_mfma_f32_16x16x32_bf16(af[kk][mi], bfr[kk][ni], acc[mi][ni], 0, 0, 0);
  }

  C += (long)blockIdx.z * sC;
  if (GEGLU) {
    // B rows g/u-interleaved at 16-col granularity: ni=0/1 g/u pair 0, ni=2/3 pair 1.
#pragma unroll
    for (int mi = 0; mi < MI; ++mi) {
      int row = m0 + wr * (BM / 2) + mi * 16 + lk * 4;
#pragma unroll
      for (int np = 0; np < 2; ++np) {
        int col = (n0 + wc * 64) / 2 + np * 16 + lr;
#pragma unroll
        for (int j = 0; j < 4; ++j) {
          float g = acc[mi][2 * np][j], u = acc[mi][2 * np + 1][j];
          float z = 0.7978845608028654f * (g + 0.044715f * g * g * g);
          float th = 2.0f / (1.0f + __expf(-2.0f * z)) - 1.0f;
          cstore(C, (size_t)(row + j) * ldc + col, 0.5f * g * (1.0f + th) * u);
        }
      }
    }
  } else {
#pragma unroll
    for (int mi = 0; mi < MI; ++mi) {
      int row = m0 + wr * (BM / 2) + mi * 16 + lk * 4;
#pragma unroll
      for (int ni = 0; ni < 4; ++ni) {
        int col = n0 + wc * 64 + ni * 16 + lr;
        if (col < nmax)
#pragma unroll
          for (int j = 0; j < 4; ++j)
            cstore(C, (size_t)(row + j) * ldc + col, acc[mi][ni][j] * alpha);
      }
    }
  }
}

// ---- fused softmax + PV ----
// grid (2, 16, 4): z=head, y=64-row q-block, x=128 of 256 out cols.
// scp[z][1024][1024] fp32 scores (pre-scaled). isfull: causal; else sliding 512.
// A-fragments built in registers from scp with exp(s-m)*invl, band-masked.
__global__ __launch_bounds__(256) void pv_fused(
    const float* __restrict__ scp, const u16* __restrict__ vt,
    u16* __restrict__ o, int isfull) {
  __shared__ __align__(16) u16 Bs[2 * 128 * 64];
  __shared__ float mrow[64], invl[64];
  const int z = blockIdx.z, m0 = blockIdx.y * 64, n0 = blockIdx.x * 128;
  const float* S_ = scp + (size_t)z * 1024 * 1024;
  const int t = threadIdx.x;

  {  // stats pre-pass: 4 threads per row (quad-local shuffles)
    int r = t >> 2, q = t & 3;
    int row = m0 + r;
    int lo = isfull ? 0 : (row - 511 > 0 ? row - 511 : 0);
    const float* rp = S_ + (size_t)row * 1024;
    float mx = -1e30f;
    for (int j = lo + q; j <= row; j += 4) mx = fmaxf(mx, rp[j]);
    mx = fmaxf(mx, __shfl_xor(mx, 1));
    mx = fmaxf(mx, __shfl_xor(mx, 2));
    float sum = 0.0f;
    for (int j = lo + q; j <= row; j += 4) sum += __expf(rp[j] - mx);
    sum += __shfl_xor(sum, 1);
    sum += __shfl_xor(sum, 2);
    if (q == 0) { mrow[r] = mx; invl[r] = 1.0f / sum; }
  }
  __syncthreads();

  const int l = t & 63, w = t >> 6;
  const int wr = w >> 1, wc = w & 1;
  const int lr = l & 15, lk = l >> 4;
  const int axr = lr & 7;
  const int srow = t >> 3;
  const int scolx = ((t & 7) ^ (srow & 7)) << 3;
  const u16* Bg = vt + (size_t)(n0 + srow) * 1024 + scolx;
  int klo = isfull ? 0 : (m0 - 512 > 0 ? m0 - 512 : 0);
  int khi = m0 + 64;
  const int nsteps = (khi - klo) >> 6;

  auto stageB = [&](int db, int k0) {
    u16* bl = Bs + db * 8192 + w * 512;
#pragma unroll
    for (int p = 0; p < 4; ++p)
      GLOAD16(Bg + k0 + (size_t)(32 * p) * 1024, bl + p * 2048);
  };
  stageB(0, klo);

  int rowi[2]; float ms[2], ls[2];
#pragma unroll
  for (int i = 0; i < 2; ++i) {
    rowi[i] = wr * 32 + i * 16 + lr;
    ms[i] = mrow[rowi[i]];
    ls[i] = invl[rowi[i]];
  }

  f32x4 acc[2][4] = {};
  for (int s = 0; s < nsteps; ++s) {
    __syncthreads();
    const int db = s & 1;
    if (s + 1 < nsteps) stageB(db ^ 1, klo + (s + 1) * 64);
    const int k0 = klo + s * 64;
    bf16x8 af[2][2];
#pragma unroll
    for (int kk = 0; kk < 2; ++kk)
#pragma unroll
      for (int i = 0; i < 2; ++i) {
        int row = m0 + rowi[i];
        int kb = k0 + kk * 32 + lk * 8;
        const float* ap = S_ + (size_t)row * 1024 + kb;
        float4 v0 = *(const float4*)ap;
        float4 v1 = *(const float4*)(ap + 4);
        float vv[8] = {v0.x, v0.y, v0.z, v0.w, v1.x, v1.y, v1.z, v1.w};
        int lo = isfull ? 0 : row - 511;
        u16 tmp[8];
#pragma unroll
        for (int e = 0; e < 8; ++e) {
          int k = kb + e;
          float pv = __expf(vv[e] - ms[i]) * ls[i];
          tmp[e] = f2bf((k >= lo && k <= row) ? pv : 0.0f);
        }
        af[kk][i] = *(bf16x8*)tmp;
      }
    const u16* Bb = Bs + db * 8192;
    bf16x8 bfr[2][4];
#pragma unroll
    for (int kk = 0; kk < 2; ++kk)
#pragma unroll
      for (int i = 0; i < 4; ++i)
        bfr[kk][i] = *(const bf16x8*)&Bb[(wc * 64 + i * 16 + lr) * 64 + (((kk * 4 + lk) ^ axr) << 3)];
#pragma unroll
    for (int kk = 0; kk < 2; ++kk)
#pragma unroll
      for (int mi = 0; mi < 2; ++mi)
#pragma unroll
        for (int ni = 0; ni < 4; ++ni)
          acc[mi][ni] = __builtin_amdgcn_mfma_f32_16x16x32_bf16(af[kk][mi], bfr[kk][ni], acc[mi][ni], 0, 0, 0);
  }

#pragma unroll
  for (int mi = 0; mi < 2; ++mi) {
    int row = m0 + wr * 32 + mi * 16 + lk * 4;
#pragma unroll
    for (int ni = 0; ni < 4; ++ni) {
      int col = z * 256 + n0 + wc * 64 + ni * 16 + lr;
#pragma unroll
      for (int j = 0; j < 4; ++j)
        o[(size_t)(row + j) * 1024 + col] = f2bf(acc[mi][ni][j]);
    }
  }
}

// ---- small kernels ----
__global__ void conv_bf16_kernel(const float* __restrict__ in, u16* __restrict__ out, long n4) {
  for (long i = (long)blockIdx.x * blockDim.x + threadIdx.x; i < n4; i += (long)gridDim.x * blockDim.x) {
    float4 v = ((const float4*)in)[i];
    ushort4 o4 = { f2bf(v.x), f2bf(v.y), f2bf(v.z), f2bf(v.w) };
    ((ushort4*)out)[i] = o4;
  }
}

__global__ void gather_kernel(const int* __restrict__ ids, const float* __restrict__ embed,
                              float* __restrict__ h) {
  int s = blockIdx.x;
  const float* src = embed + (size_t)ids[s] * 640;
  float scale = sqrtf(640.0f);
  for (int c = threadIdx.x; c < 640; c += blockDim.x)
    h[(size_t)s * 640 + c] = src[c] * scale;
}

__global__ void rms_to_bf16(const float* __restrict__ in, const float* __restrict__ w,
                            u16* __restrict__ out, int n) {
  __shared__ float red[8];
  int row = blockIdx.x;
  const float* x = in + (size_t)row * n;
  float ss = 0.0f;
  for (int c = threadIdx.x; c < n; c += blockDim.x) { float v = x[c]; ss += v * v; }
  ss = blockSum(ss, red);
  float sc = rsqrtf(ss / (float)n + 1e-6f);
  for (int c = threadIdx.x; c < n; c += blockDim.x)
    out[(size_t)row * n + c] = f2bf(x[c] * sc * (1.0f + w[c]));
}

// h += rms(sum_z t1[z], wa); xout = bf16(rms(h, wn))
__global__ void fused_add_norm(float* __restrict__ h, const float* __restrict__ t1,
                               int nsl, const float* __restrict__ wa,
                               const float* __restrict__ wn, u16* __restrict__ xout) {
  __shared__ float red[8];
  const int row = blockIdx.x, t = threadIdx.x;
  float ts[3], hv[3];
  float ss = 0.0f;
#pragma unroll
  for (int i = 0; i < 3; ++i) {
    int c = t + i * 256;
    float v = 0.0f;
    if (c < 640) {
      v = t1[(size_t)row * 640 + c];
      for (int z = 1; z < nsl; ++z) v += t1[(size_t)z * 655360 + (size_t)row * 640 + c];
    }
    ts[i] = v; ss += v * v;
  }
  ss = blockSum(ss, red);
  const float s1 = rsqrtf(ss * (1.0f / 640.0f) + 1e-6f);
  float ss2 = 0.0f;
#pragma unroll
  for (int i = 0; i < 3; ++i) {
    int c = t + i * 256;
    float v = 0.0f;
    if (c < 640) v = h[(size_t)row * 640 + c] + ts[i] * s1 * (1.0f + wa[c]);
    hv[i] = v; ss2 += v * v;
  }
  ss2 = blockSum(ss2, red);
  const float s2 = rsqrtf(ss2 * (1.0f / 640.0f) + 1e-6f);
#pragma unroll
  for (int i = 0; i < 3; ++i) {
    int c = t + i * 256;
    if (c < 640) {
      h[(size_t)row * 640 + c] = hv[i];
      xout[(size_t)row * 640 + c] = f2bf(hv[i] * s2 * (1.0f + wn[c]));
    }
  }
}

__global__ void rope_tables_kernel(float* cg, float* sg, float* cl, float* sl) {
  int s = blockIdx.x, t = threadIdx.x;  // t < 128
  float e = -(float)t * (1.0f / 128.0f);
  float ag = (float)s * expf(e * logf(1000000.0f));
  float al = (float)s * expf(e * logf(10000.0f));
  cg[s * 128 + t] = cosf(ag); sg[s * 128 + t] = sinf(ag);
  cl[s * 128 + t] = cosf(al); sl[s * 128 + t] = sinf(al);
}

// per (s, unit): unit 0..3 Q heads (rms+rope), 4 K (rms+rope), 5 V transpose
__global__ void rope_fused(const float* __restrict__ qkvf, const float* __restrict__ qn,
                           const float* __restrict__ kn, u16* __restrict__ qb,
                           u16* __restrict__ kb, u16* __restrict__ vt,
                           const float* __restrict__ ct, const float* __restrict__ st) {
  __shared__ float red[8];
  __shared__ float sh[256];
  const int s = blockIdx.x, hh = blockIdx.y, t = threadIdx.x;
  if (hh == 5) {
    vt[(size_t)t * 1024 + s] = f2bf(qkvf[(size_t)s * 1536 + 1280 + t]);
    return;
  }
  const float* src = qkvf + (size_t)s * 1536 + hh * 256;  // hh==4 -> K at 1024
  const float* nw = (hh == 4) ? kn : qn;
  float x = src[t];
  float ss = blockSum(x * x, red);
  float n = x * rsqrtf(ss * (1.0f / 256.0f) + 1e-6f) * (1.0f + nw[t]);
  sh[t] = n;
  __syncthreads();
  float cosv = ct[s * 128 + (t & 127)];
  float sinv = st[s * 128 + (t & 127)];
  float partner = (t < 128) ? -sh[t + 128] : sh[t - 128];
  u16 r = f2bf(n * cosv + partner * sinv);
  if (hh == 4) kb[(size_t)s * 256 + t] = r;
  else qb[((size_t)hh * 1024 + s) * 256 + t] = r;
}

// transpose + bf16-convert per-layer weights; 64x64 tiles; blockIdx.y = layer.
// wg/wu interleave into wguT rows at 16-col granularity.
__global__ void transpose7_kernel(
    const float* s0, const float* s1, const float* s2, const float* s3,
    const float* s4, const float* s5, const float* s6,
    u16* d0, u16* d1, u16* d2, u16* d3, u16* d45, u16* d6) {
  __shared__ float tile[64][65];
  const int ly = blockIdx.y;
  int b = blockIdx.x;
  const float* src; u16* dst; int K, N, idx, ilv = 0;
  if (b < 160)       { src = s0 + (size_t)ly * 655360;  dst = d0 + (size_t)ly * 983040;  K = 640;  N = 1024; idx = b; }
  else if (b < 200)  { src = s1 + (size_t)ly * 163840;  dst = d1 + (size_t)ly * 983040;  K = 640;  N = 256;  idx = b - 160; }
  else if (b < 240)  { src = s2 + (size_t)ly * 163840;  dst = d2 + (size_t)ly * 983040;  K = 640;  N = 256;  idx = b - 200; }
  else if (b < 400)  { src = s3 + (size_t)ly * 655360;  dst = d3 + (size_t)ly * 655360;  K = 1024; N = 640;  idx = b - 240; }
  else if (b < 720)  { src = s4 + (size_t)ly * 1310720; dst = d45 + (size_t)ly * 2621440; K = 640; N = 2048; idx = b - 400;  ilv = 1; }
  else if (b < 1040) { src = s5 + (size_t)ly * 1310720; dst = d45 + (size_t)ly * 2621440; K = 640; N = 2048; idx = b - 720;  ilv = 2; }
  else               { src = s6 + (size_t)ly * 1310720; dst = d6 + (size_t)ly * 1310720; K = 2048; N = 640; idx = b - 1040; }
  int tn = N >> 6;
  int kt = idx / tn, nt = idx % tn;
  int t = threadIdx.x;
  int lr = t >> 4, lc = (t & 15) * 4;
#pragma unroll
  for (int i = 0; i < 4; ++i) {
    float4 v = *(const float4*)&src[(size_t)(kt * 64 + lr + i * 16) * N + nt * 64 + lc];
    tile[lr + i * 16][lc] = v.x; tile[lr + i * 16][lc + 1] = v.y;
    tile[lr + i * 16][lc + 2] = v.z; tile[lr + i * 16][lc + 3] = v.w;
  }
  __syncthreads();
  int wn = t >> 3, wk8 = (t & 7) * 8;
#pragma unroll
  for (int i = 0; i < 2; ++i) {
    int gcol = nt * 64 + wn + i * 32;
    int drow = ilv ? ((gcol >> 4) * 32 + ((ilv == 2) ? 16 : 0) + (gcol & 15)) : gcol;
    u16 tmp[8];
#pragma unroll
    for (int j = 0; j < 8; ++j) tmp[j] = f2bf(tile[wk8 + j][wn + i * 32]);
    *(int4*)&dst[(size_t)drow * K + kt * 64 + wk8] = *(int4*)tmp;
  }
}

extern "C" void kernel_launch(void* const* d_in, const int* in_sizes, int n_in,
                              void* d_out, int out_size, void* d_ws, size_t ws_size,
                              hipStream_t stream) {
  (void)in_sizes; (void)n_in; (void)out_size;
  const int*   ids   = (const int*)d_in[0];
  // d_in[1] = is_full; deterministic (l+1)%6==0, hardcoded.
  const float* embed = (const float*)d_in[2];
  const float* wq    = (const float*)d_in[3];
  const float* wk    = (const float*)d_in[4];
  const float* wv    = (const float*)d_in[5];
  const float* wo    = (const float*)d_in[6];
  const float* qn    = (const float*)d_in[7];
  const float* kn    = (const float*)d_in[8];
  const float* ln1   = (const float*)d_in[9];
  const float* ln2   = (const float*)d_in[10];
  const float* ln3   = (const float*)d_in[11];
  const float* ln4   = (const float*)d_in[12];
  const float* wg    = (const float*)d_in[13];
  const float* wu    = (const float*)d_in[14];
  const float* wd    = (const float*)d_in[15];
  const float* nw    = (const float*)d_in[16];
  float* out = (float*)d_out;

  const int S = 1024, H = 640, NH = 4, HD = 256, I = 2048, V = 32768;
  const int BIG = 1 << 30;

  const bool batched = ws_size >= (size_t)310 * 1024 * 1024;
  const int NL = batched ? 18 : 1;

  unsigned char* p = (unsigned char*)d_ws;
  auto alloc = [&](size_t b) { void* r = (void*)p; p += (b + 255) & ~(size_t)255; return r; };
  u16*   wqkvT = (u16*)alloc((size_t)NL * 1536 * 640 * 2);
  u16*   woT   = (u16*)alloc((size_t)NL * 640 * 1024 * 2);
  u16*   wguT  = (u16*)alloc((size_t)NL * 4096 * 640 * 2);  // g/u interleaved rows
  u16*   wdT   = (u16*)alloc((size_t)NL * 640 * 2048 * 2);
  u16*   embT  = (u16*)alloc((size_t)V * H * 2);
  float* h     = (float*)alloc((size_t)S * H * 4);
  u16*   x     = (u16*)alloc((size_t)S * H * 2);
  float* qkvf  = (float*)alloc((size_t)S * 1536 * 4);
  u16*   qb    = (u16*)alloc((size_t)NH * S * HD * 2);
  u16*   kb    = (u16*)alloc((size_t)S * HD * 2);
  u16*   vt    = (u16*)alloc((size_t)HD * S * 2);
  float* scp   = (float*)alloc((size_t)NH * S * S * 4);
  u16*   o     = (u16*)alloc((size_t)S * NH * HD * 2);
  float* t1    = (float*)alloc((size_t)4 * S * H * 4);  // up to 4 split-K slices
  u16*   mg    = (u16*)alloc((size_t)S * I * 2);
  u16*   hn    = (u16*)alloc((size_t)S * H * 2);
  float* cg    = (float*)alloc((size_t)S * 128 * 4);
  float* sg    = (float*)alloc((size_t)S * 128 * 4);
  float* cl    = (float*)alloc((size_t)S * 128 * 4);
  float* sl2   = (float*)alloc((size_t)S * 128 * 4);

  rope_tables_kernel<<<S, 128, 0, stream>>>(cg, sg, cl, sl2);
  conv_bf16_kernel<<<2048, 256, 0, stream>>>(embed, embT, (long)V * H / 4);
  gather_kernel<<<S, 256, 0, stream>>>(ids, embed, h);
  rms_to_bf16<<<S, 256, 0, stream>>>(h, ln1, x, H);

  if (batched)
    transpose7_kernel<<<dim3(1360, 18), 256, 0, stream>>>(
        wq, wk, wv, wo, wg, wu, wd,
        wqkvT, wqkvT + (size_t)1024 * 640, wqkvT + (size_t)1280 * 640, woT, wguT, wdT);

  for (int l = 0; l < 18; ++l) {
    bool full = ((l + 1) % 6) == 0;
    size_t lw = batched ? (size_t)l : 0;
    u16* wqkvTl = wqkvT + lw * 1536 * 640;
    u16* woTl   = woT   + lw * 640 * 1024;
    u16* wguTl  = wguT  + lw * 4096 * 640;
    u16* wdTl   = wdT   + lw * 640 * 2048;

    if (!batched)
      transpose7_kernel<<<dim3(1360, 1), 256, 0, stream>>>(
          wq + (size_t)l * H * 1024, wk + (size_t)l * H * 256, wv + (size_t)l * H * 256,
          wo + (size_t)l * 1024 * H, wg + (size_t)l * H * I, wu + (size_t)l * H * I,
          wd + (size_t)l * I * H,
          wqkvTl, wqkvTl + (size_t)1024 * 640, wqkvTl + (size_t)1280 * 640, woTl, wguTl, wdTl);

    gemm_nt<float, 0, 64><<<dim3(12, 16, 1), 256, 0, stream>>>(
        x, H, 0, wqkvTl, H, 0, qkvf, 1536, 0, H, 1.0f, 0, -1, 1, BIG);
    rope_fused<<<dim3(S, 6), 256, 0, stream>>>(qkvf, qn + l * HD, kn + l * HD, qb, kb, vt,
                                               full ? cg : cl, full ? sg : sl2);
    if (full)
      gemm_nt<float, 0, 64><<<dim3(8, 16, NH), 256, 0, stream>>>(
          qb, HD, (long)S * HD, kb, HD, 0, scp, S, (long)S * S, HD, 0.0625f, 0, -2, 1, BIG);
    else
      gemm_nt<float, 0, 64><<<dim3(5, 16, NH), 256, 0, stream>>>(
          qb, HD, (long)S * HD, kb, HD, 0, scp, S, (long)S * S, HD, 0.0625f, 0, 512, 1, S);
    pv_fused<<<dim3(2, 16, NH), 256, 0, stream>>>(scp, vt, o, full ? 1 : 0);
    gemm_nt<float, 0, 64><<<dim3(5, 16, 2), 256, 0, stream>>>(
        o, NH * HD, 0, woTl, NH * HD, 0, t1, H, (long)S * H, NH * HD, 1.0f, 3, -1, 2, BIG);
    fused_add_norm<<<S, 256, 0, stream>>>(h, t1, 2, ln2 + l * H, ln3 + l * H, x);

    gemm_nt<u16, 1, 128><<<dim3(32, 8, 1), 256, 0, stream>>>(
        x, H, 0, wguTl, H, 0, mg, I, 0, H, 1.0f, 0, -1, 1, BIG);
    gemm_nt<float, 0, 64><<<dim3(5, 16, 4), 256, 0, stream>>>(
        mg, I, 0, wdTl, I, 0, t1, H, (long)S * H, I, 1.0f, 3, -1, 4, BIG);
    fused_add_norm<<<S, 256, 0, stream>>>(h, t1, 4, ln4 + l * H,
                                          (l == 17) ? nw : ln1 + (l + 1) * H,
                                          (l == 17) ? hn : x);
  }

  gemm_nt<float, 0, 128><<<dim3(V / 128, 8, 1), 256, 0, stream>>>(
      hn, H, 0, embT, H, 0, out, V, 0, H, 1.0f, 0, -1, 1, BIG);
}

// Round 7
// 2200.608 us; speedup vs baseline: 1.2024x; 1.2024x over previous
//
#include <hip/hip_runtime.h>

// Gemma3 forward, MI355X. Round 7: round-4 proven GEMM configs (BM=128,
// softmax+PV path) + batched all-layer weight transpose + fused gather+RMS.
// L=18 H=640 NH=4 NKV=1 HD=256 I=2048 V=32768 B=1 S=1024 WINDOW=512

typedef unsigned short u16;
typedef __attribute__((ext_vector_type(4))) float f32x4;
typedef __attribute__((ext_vector_type(8))) short bf16x8;

#define DEV static __device__ __forceinline__

DEV u16 f2bf(float f) {  // round-to-nearest-even fp32 -> bf16
  union { float f; unsigned u; } x; x.f = f;
  unsigned r = x.u + 0x7fffu + ((x.u >> 16) & 1u);
  return (u16)(r >> 16);
}

#define GLOAD16(gp, lp) __builtin_amdgcn_global_load_lds( \
    (const __attribute__((address_space(1))) void*)(gp), \
    (__attribute__((address_space(3))) void*)(lp), 16, 0, 0)

DEV float blockSum(float v, float* red) {
#pragma unroll
  for (int o = 32; o; o >>= 1) v += __shfl_down(v, o);
  int lane = threadIdx.x & 63, wid = threadIdx.x >> 6;
  if (lane == 0) red[wid] = v;
  __syncthreads();
  float s = red[0] + red[1] + red[2] + red[3];
  __syncthreads();
  return s;
}

DEV float blockMax(float v, float* red) {
#pragma unroll
  for (int o = 32; o; o >>= 1) v = fmaxf(v, __shfl_down(v, o));
  int lane = threadIdx.x & 63, wid = threadIdx.x >> 6;
  if (lane == 0) red[wid] = v;
  __syncthreads();
  float s = fmaxf(fmaxf(red[0], red[1]), fmaxf(red[2], red[3]));
  __syncthreads();
  return s;
}

DEV void cstore(float* C, size_t i, float v) { C[i] = v; }
DEV void cstore(u16* C, size_t i, float v) { C[i] = f2bf(v); }

// ---- GEMM NT: C[M,N] = alpha * A[M,K]bf16 * (B[N,K]bf16)^T ----
// 128x128 tile, BK=64, double-buffered LDS, depth-1 prefetch, XOR-swizzled LDS
// (pre-swizzled global source, linear global_load_lds dest).
// nshift: -1 plain; -2 causal tile-skip; >=0 sliding band n0=m0-nshift+bx*128.
// kmode: 0 full K; 1 sliding K-band; 2 causal K-band; 3 split-K over blockIdx.z.
// GEGLU=1: B rows g/u-interleaved at 16-col granularity; epilogue writes
// bf16 gelu(g)*u, N/2 output cols.
template <typename CT, int GEGLU>
__global__ __launch_bounds__(256) void gemm_nt(
    const u16* __restrict__ A, int lda, long sA,
    const u16* __restrict__ B, int ldb, long sB,
    CT* __restrict__ C, int ldc, long sC,
    int K, float alpha, int kmode, int nshift, int ksplit) {
  __shared__ __align__(16) u16 As[2 * 128 * 64];
  __shared__ __align__(16) u16 Bs[2 * 128 * 64];
  const int m0 = blockIdx.y * 128;
  int n0;
  if (nshift == -1) n0 = blockIdx.x * 128;
  else if (nshift == -2) { n0 = blockIdx.x * 128; if (n0 > m0) return; }
  else { n0 = m0 - nshift + blockIdx.x * 128; if (n0 < 0) return; }
  int klo = 0, khi = K;
  if (kmode == 1) { klo = m0 - 512; if (klo < 0) klo = 0; khi = m0 + 128; if (khi > K) khi = K; }
  else if (kmode == 2) { khi = m0 + 128; if (khi > K) khi = K; }
  else if (kmode == 3) { int kl = K / ksplit; klo = blockIdx.z * kl; khi = klo + kl; }
  A += (long)blockIdx.z * sA;
  B += (long)blockIdx.z * sB;

  const int t = threadIdx.x;
  const int l = t & 63, w = t >> 6;
  const int wr = w >> 1, wc = w & 1;        // 2x2 waves, each 64x64 out
  const int lr = l & 15, lk = l >> 4;
  const int axr = lr & 7;                   // ds_read swizzle key
  const int srow = t >> 3;                  // staging row 0..31 (+32p)
  const int scolx = ((t & 7) ^ (srow & 7)) << 3;  // pre-swizzled global col
  const u16* Ag = A + (size_t)(m0 + srow) * lda + scolx;
  const u16* Bg = B + (size_t)(n0 + srow) * ldb + scolx;
  const int nsteps = (khi - klo) >> 6;

  auto stage = [&](int db, int k0) {
    const u16* a = Ag + k0;
    const u16* b = Bg + k0;
    u16* al = As + db * 8192 + w * 512;     // wave-uniform LDS bases
    u16* bl = Bs + db * 8192 + w * 512;
#pragma unroll
    for (int p = 0; p < 4; ++p) {
      GLOAD16(a + (size_t)(32 * p) * lda, al + p * 2048);
      GLOAD16(b + (size_t)(32 * p) * ldb, bl + p * 2048);
    }
  };

  stage(0, klo);
  f32x4 acc[4][4] = {};

  for (int s = 0; s < nsteps; ++s) {
    __syncthreads();                        // drains prefetch; joins prior ds_reads
    const int db = s & 1;
    if (s + 1 < nsteps) stage(db ^ 1, klo + (s + 1) * 64);
    const u16* Ab = As + db * 8192;
    const u16* Bb = Bs + db * 8192;
    bf16x8 af[2][4], bfr[2][4];
#pragma unroll
    for (int kk = 0; kk < 2; ++kk)
#pragma unroll
      for (int i = 0; i < 4; ++i) {
        af[kk][i]  = *(const bf16x8*)&Ab[(wr * 64 + i * 16 + lr) * 64 + (((kk * 4 + lk) ^ axr) << 3)];
        bfr[kk][i] = *(const bf16x8*)&Bb[(wc * 64 + i * 16 + lr) * 64 + (((kk * 4 + lk) ^ axr) << 3)];
      }
#pragma unroll
    for (int kk = 0; kk < 2; ++kk)
#pragma unroll
      for (int mi = 0; mi < 4; ++mi)
#pragma unroll
        for (int ni = 0; ni < 4; ++ni)
          acc[mi][ni] = __builtin_amdgcn_mfma_f32_16x16x32_bf16(af[kk][mi], bfr[kk][ni], acc[mi][ni], 0, 0, 0);
  }

  C += (long)blockIdx.z * sC;
  if (GEGLU) {
    // acc[ni]: B rows n0+wc*64+ni*16+lr; rows (r&31)<16 are g, >=16 are u.
#pragma unroll
    for (int mi = 0; mi < 4; ++mi) {
      int row = m0 + wr * 64 + mi * 16 + lk * 4;
#pragma unroll
      for (int np = 0; np < 2; ++np) {
        int col = (n0 + wc * 64) / 2 + np * 16 + lr;
#pragma unroll
        for (int j = 0; j < 4; ++j) {
          float g = acc[mi][2 * np][j], u = acc[mi][2 * np + 1][j];
          float z = 0.7978845608028654f * (g + 0.044715f * g * g * g);
          float th = 2.0f / (1.0f + __expf(-2.0f * z)) - 1.0f;
          cstore(C, (size_t)(row + j) * ldc + col, 0.5f * g * (1.0f + th) * u);
        }
      }
    }
  } else {
#pragma unroll
    for (int mi = 0; mi < 4; ++mi) {
      int row = m0 + wr * 64 + mi * 16 + lk * 4;
#pragma unroll
      for (int ni = 0; ni < 4; ++ni) {
        int col = n0 + wc * 64 + ni * 16 + lr;
#pragma unroll
        for (int j = 0; j < 4; ++j)
          cstore(C, (size_t)(row + j) * ldc + col, acc[mi][ni][j] * alpha);
      }
    }
  }
}

// ---- small kernels ----
__global__ void conv_bf16_kernel(const float* __restrict__ in, u16* __restrict__ out, long n4) {
  for (long i = (long)blockIdx.x * blockDim.x + threadIdx.x; i < n4; i += (long)gridDim.x * blockDim.x) {
    float4 v = ((const float4*)in)[i];
    ushort4 o4 = { f2bf(v.x), f2bf(v.y), f2bf(v.z), f2bf(v.w) };
    ((ushort4*)out)[i] = o4;
  }
}

// h = embed[ids[s]] * sqrt(H); x = bf16(rms(h, ln1))
__global__ void gather_rms_kernel(const int* __restrict__ ids, const float* __restrict__ embed,
                                  const float* __restrict__ w, float* __restrict__ h,
                                  u16* __restrict__ x) {
  __shared__ float red[8];
  const int s = blockIdx.x, t = threadIdx.x;
  const float* src = embed + (size_t)ids[s] * 640;
  const float scale = sqrtf(640.0f);
  float hv[3];
  float ss = 0.0f;
#pragma unroll
  for (int i = 0; i < 3; ++i) {
    int c = t + i * 256;
    float v = (c < 640) ? src[c] * scale : 0.0f;
    hv[i] = v; ss += v * v;
  }
  ss = blockSum(ss, red);
  const float sc = rsqrtf(ss * (1.0f / 640.0f) + 1e-6f);
#pragma unroll
  for (int i = 0; i < 3; ++i) {
    int c = t + i * 256;
    if (c < 640) {
      h[(size_t)s * 640 + c] = hv[i];
      x[(size_t)s * 640 + c] = f2bf(hv[i] * sc * (1.0f + w[c]));
    }
  }
}

__global__ void rms_to_bf16(const float* __restrict__ in, const float* __restrict__ w,
                            u16* __restrict__ out, int n) {
  __shared__ float red[8];
  int row = blockIdx.x;
  const float* x = in + (size_t)row * n;
  float ss = 0.0f;
  for (int c = threadIdx.x; c < n; c += blockDim.x) { float v = x[c]; ss += v * v; }
  ss = blockSum(ss, red);
  float sc = rsqrtf(ss / (float)n + 1e-6f);
  for (int c = threadIdx.x; c < n; c += blockDim.x)
    out[(size_t)row * n + c] = f2bf(x[c] * sc * (1.0f + w[c]));
}

// h += rms(sum_z t1[z], wa); xout = bf16(rms(h, wn))
__global__ void fused_add_norm(float* __restrict__ h, const float* __restrict__ t1,
                               int nsl, const float* __restrict__ wa,
                               const float* __restrict__ wn, u16* __restrict__ xout) {
  __shared__ float red[8];
  const int row = blockIdx.x, t = threadIdx.x;
  float ts[3], hv[3];
  float ss = 0.0f;
#pragma unroll
  for (int i = 0; i < 3; ++i) {
    int c = t + i * 256;
    float v = 0.0f;
    if (c < 640) {
      v = t1[(size_t)row * 640 + c];
      for (int z = 1; z < nsl; ++z) v += t1[(size_t)z * 655360 + (size_t)row * 640 + c];
    }
    ts[i] = v; ss += v * v;
  }
  ss = blockSum(ss, red);
  const float s1 = rsqrtf(ss * (1.0f / 640.0f) + 1e-6f);
  float ss2 = 0.0f;
#pragma unroll
  for (int i = 0; i < 3; ++i) {
    int c = t + i * 256;
    float v = 0.0f;
    if (c < 640) v = h[(size_t)row * 640 + c] + ts[i] * s1 * (1.0f + wa[c]);
    hv[i] = v; ss2 += v * v;
  }
  ss2 = blockSum(ss2, red);
  const float s2 = rsqrtf(ss2 * (1.0f / 640.0f) + 1e-6f);
#pragma unroll
  for (int i = 0; i < 3; ++i) {
    int c = t + i * 256;
    if (c < 640) {
      h[(size_t)row * 640 + c] = hv[i];
      xout[(size_t)row * 640 + c] = f2bf(hv[i] * s2 * (1.0f + wn[c]));
    }
  }
}

__global__ void rope_tables_kernel(float* cg, float* sg, float* cl, float* sl) {
  int s = blockIdx.x, t = threadIdx.x;  // t < 128
  float e = -(float)t * (1.0f / 128.0f);
  float ag = (float)s * expf(e * logf(1000000.0f));
  float al = (float)s * expf(e * logf(10000.0f));
  cg[s * 128 + t] = cosf(ag); sg[s * 128 + t] = sinf(ag);
  cl[s * 128 + t] = cosf(al); sl[s * 128 + t] = sinf(al);
}

// per (s, unit): unit 0..3 Q heads (rms+rope), 4 K (rms+rope), 5 V transpose
__global__ void rope_fused(const float* __restrict__ qkvf, const float* __restrict__ qn,
                           const float* __restrict__ kn, u16* __restrict__ qb,
                           u16* __restrict__ kb, u16* __restrict__ vt,
                           const float* __restrict__ ct, const float* __restrict__ st) {
  __shared__ float red[8];
  __shared__ float sh[256];
  const int s = blockIdx.x, hh = blockIdx.y, t = threadIdx.x;
  if (hh == 5) {
    vt[(size_t)t * 1024 + s] = f2bf(qkvf[(size_t)s * 1536 + 1280 + t]);
    return;
  }
  const float* src = qkvf + (size_t)s * 1536 + hh * 256;  // hh==4 -> K at 1024
  const float* nw = (hh == 4) ? kn : qn;
  float x = src[t];
  float ss = blockSum(x * x, red);
  float n = x * rsqrtf(ss * (1.0f / 256.0f) + 1e-6f) * (1.0f + nw[t]);
  sh[t] = n;
  __syncthreads();
  float cosv = ct[s * 128 + (t & 127)];
  float sinv = st[s * 128 + (t & 127)];
  float partner = (t < 128) ? -sh[t + 128] : sh[t - 128];
  u16 r = f2bf(n * cosv + partner * sinv);
  if (hh == 4) kb[(size_t)s * 256 + t] = r;
  else qb[((size_t)hh * 1024 + s) * 256 + t] = r;
}

// masked softmax; writes P over exactly the band PV reads. mode 1 sliding, 0 causal
__global__ void softmax_kernel(const float* __restrict__ sc, u16* __restrict__ P, int mode) {
  __shared__ float red[8];
  const int i = blockIdx.x, hh = blockIdx.y, t = threadIdx.x;
  const float* row = sc + ((size_t)hh * 1024 + i) * 1024;
  u16* prow = P + ((size_t)hh * 1024 + i) * 1024;
  const int m0 = i & ~127;
  int lo = 0, wlo = 0;
  if (mode) {
    lo = i - 511; if (lo < 0) lo = 0;
    wlo = m0 - 512; if (wlo < 0) wlo = 0;
  }
  const int whi = m0 + 127;
  float m = -1e30f;
  for (int j = lo + t; j <= i; j += 256) m = fmaxf(m, row[j]);
  m = blockMax(m, red);
  float sum = 0.0f;
  for (int j = lo + t; j <= i; j += 256) sum += __expf(row[j] - m);
  sum = blockSum(sum, red);
  float inv = 1.0f / sum;
  for (int j = wlo + t; j <= whi; j += 256) {
    float v = (j >= lo && j <= i) ? __expf(row[j] - m) * inv : 0.0f;
    prow[j] = f2bf(v);
  }
}

// transpose + bf16-convert per-layer weights; 64x64 tiles; blockIdx.y = layer.
// wg/wu interleave into wguT rows at 16-col granularity.
__global__ void transpose7_kernel(
    const float* s0, const float* s1, const float* s2, const float* s3,
    const float* s4, const float* s5, const float* s6,
    u16* d0, u16* d1, u16* d2, u16* d3, u16* d45, u16* d6) {
  __shared__ float tile[64][65];
  const int ly = blockIdx.y;
  int b = blockIdx.x;
  const float* src; u16* dst; int K, N, idx, ilv = 0;
  if (b < 160)       { src = s0 + (size_t)ly * 655360;  dst = d0 + (size_t)ly * 983040;  K = 640;  N = 1024; idx = b; }
  else if (b < 200)  { src = s1 + (size_t)ly * 163840;  dst = d1 + (size_t)ly * 983040;  K = 640;  N = 256;  idx = b - 160; }
  else if (b < 240)  { src = s2 + (size_t)ly * 163840;  dst = d2 + (size_t)ly * 983040;  K = 640;  N = 256;  idx = b - 200; }
  else if (b < 400)  { src = s3 + (size_t)ly * 655360;  dst = d3 + (size_t)ly * 655360;  K = 1024; N = 640;  idx = b - 240; }
  else if (b < 720)  { src = s4 + (size_t)ly * 1310720; dst = d45 + (size_t)ly * 2621440; K = 640; N = 2048; idx = b - 400;  ilv = 1; }
  else if (b < 1040) { src = s5 + (size_t)ly * 1310720; dst = d45 + (size_t)ly * 2621440; K = 640; N = 2048; idx = b - 720;  ilv = 2; }
  else               { src = s6 + (size_t)ly * 1310720; dst = d6 + (size_t)ly * 1310720; K = 2048; N = 640; idx = b - 1040; }
  int tn = N >> 6;
  int kt = idx / tn, nt = idx % tn;
  int t = threadIdx.x;
  int lr = t >> 4, lc = (t & 15) * 4;
#pragma unroll
  for (int i = 0; i < 4; ++i) {
    float4 v = *(const float4*)&src[(size_t)(kt * 64 + lr + i * 16) * N + nt * 64 + lc];
    tile[lr + i * 16][lc] = v.x; tile[lr + i * 16][lc + 1] = v.y;
    tile[lr + i * 16][lc + 2] = v.z; tile[lr + i * 16][lc + 3] = v.w;
  }
  __syncthreads();
  int wn = t >> 3, wk8 = (t & 7) * 8;
#pragma unroll
  for (int i = 0; i < 2; ++i) {
    int gcol = nt * 64 + wn + i * 32;
    int drow = ilv ? ((gcol >> 4) * 32 + ((ilv == 2) ? 16 : 0) + (gcol & 15)) : gcol;
    u16 tmp[8];
#pragma unroll
    for (int j = 0; j < 8; ++j) tmp[j] = f2bf(tile[wk8 + j][wn + i * 32]);
    *(int4*)&dst[(size_t)drow * K + kt * 64 + wk8] = *(int4*)tmp;
  }
}

extern "C" void kernel_launch(void* const* d_in, const int* in_sizes, int n_in,
                              void* d_out, int out_size, void* d_ws, size_t ws_size,
                              hipStream_t stream) {
  (void)in_sizes; (void)n_in; (void)out_size;
  const int*   ids   = (const int*)d_in[0];
  // d_in[1] = is_full; deterministic (l+1)%6==0, hardcoded.
  const float* embed = (const float*)d_in[2];
  const float* wq    = (const float*)d_in[3];
  const float* wk    = (const float*)d_in[4];
  const float* wv    = (const float*)d_in[5];
  const float* wo    = (const float*)d_in[6];
  const float* qn    = (const float*)d_in[7];
  const float* kn    = (const float*)d_in[8];
  const float* ln1   = (const float*)d_in[9];
  const float* ln2   = (const float*)d_in[10];
  const float* ln3   = (const float*)d_in[11];
  const float* ln4   = (const float*)d_in[12];
  const float* wg    = (const float*)d_in[13];
  const float* wu    = (const float*)d_in[14];
  const float* wd    = (const float*)d_in[15];
  const float* nw    = (const float*)d_in[16];
  float* out = (float*)d_out;

  const int S = 1024, H = 640, NH = 4, HD = 256, I = 2048, V = 32768;

  const bool batched = ws_size >= (size_t)310 * 1024 * 1024;
  const int NL = batched ? 18 : 1;

  unsigned char* p = (unsigned char*)d_ws;
  auto alloc = [&](size_t b) { void* r = (void*)p; p += (b + 255) & ~(size_t)255; return r; };
  u16*   wqkvT = (u16*)alloc((size_t)NL * 1536 * 640 * 2);
  u16*   woT   = (u16*)alloc((size_t)NL * 640 * 1024 * 2);
  u16*   wguT  = (u16*)alloc((size_t)NL * 4096 * 640 * 2);  // g/u interleaved rows
  u16*   wdT   = (u16*)alloc((size_t)NL * 640 * 2048 * 2);
  u16*   embT  = (u16*)alloc((size_t)V * H * 2);
  float* h     = (float*)alloc((size_t)S * H * 4);
  u16*   x     = (u16*)alloc((size_t)S * H * 2);
  float* qkvf  = (float*)alloc((size_t)S * 1536 * 4);
  u16*   qb    = (u16*)alloc((size_t)NH * S * HD * 2);
  u16*   kb    = (u16*)alloc((size_t)S * HD * 2);
  u16*   vt    = (u16*)alloc((size_t)HD * S * 2);
  float* scp   = (float*)alloc((size_t)NH * S * S * 4);
  u16*   P     = (u16*)alloc((size_t)NH * S * S * 2);
  u16*   o     = (u16*)alloc((size_t)S * NH * HD * 2);
  float* t1    = (float*)alloc((size_t)4 * S * H * 4);  // up to 4 split-K slices
  u16*   mg    = (u16*)alloc((size_t)S * I * 2);
  u16*   hn    = (u16*)alloc((size_t)S * H * 2);
  float* cg    = (float*)alloc((size_t)S * 128 * 4);
  float* sg    = (float*)alloc((size_t)S * 128 * 4);
  float* cl    = (float*)alloc((size_t)S * 128 * 4);
  float* sl2   = (float*)alloc((size_t)S * 128 * 4);

  rope_tables_kernel<<<S, 128, 0, stream>>>(cg, sg, cl, sl2);
  conv_bf16_kernel<<<2048, 256, 0, stream>>>(embed, embT, (long)V * H / 4);
  gather_rms_kernel<<<S, 256, 0, stream>>>(ids, embed, ln1, h, x);

  if (batched)
    transpose7_kernel<<<dim3(1360, 18), 256, 0, stream>>>(
        wq, wk, wv, wo, wg, wu, wd,
        wqkvT, wqkvT + (size_t)1024 * 640, wqkvT + (size_t)1280 * 640, woT, wguT, wdT);

  for (int l = 0; l < 18; ++l) {
    bool full = ((l + 1) % 6) == 0;
    size_t lw = batched ? (size_t)l : 0;
    u16* wqkvTl = wqkvT + lw * 1536 * 640;
    u16* woTl   = woT   + lw * 640 * 1024;
    u16* wguTl  = wguT  + lw * 4096 * 640;
    u16* wdTl   = wdT   + lw * 640 * 2048;

    if (!batched)
      transpose7_kernel<<<dim3(1360, 1), 256, 0, stream>>>(
          wq + (size_t)l * H * 1024, wk + (size_t)l * H * 256, wv + (size_t)l * H * 256,
          wo + (size_t)l * 1024 * H, wg + (size_t)l * H * I, wu + (size_t)l * H * I,
          wd + (size_t)l * I * H,
          wqkvTl, wqkvTl + (size_t)1024 * 640, wqkvTl + (size_t)1280 * 640, woTl, wguTl, wdTl);

    gemm_nt<float, 0><<<dim3(12, 8, 1), 256, 0, stream>>>(
        x, H, 0, wqkvTl, H, 0, qkvf, 1536, 0, H, 1.0f, 0, -1, 1);
    rope_fused<<<dim3(S, 6), 256, 0, stream>>>(qkvf, qn + l * HD, kn + l * HD, qb, kb, vt,
                                               full ? cg : cl, full ? sg : sl2);
    if (full)
      gemm_nt<float, 0><<<dim3(8, 8, NH), 256, 0, stream>>>(
          qb, HD, (long)S * HD, kb, HD, 0, scp, S, (long)S * S, HD, 0.0625f, 0, -2, 1);
    else
      gemm_nt<float, 0><<<dim3(5, 8, NH), 256, 0, stream>>>(
          qb, HD, (long)S * HD, kb, HD, 0, scp, S, (long)S * S, HD, 0.0625f, 0, 512, 1);
    softmax_kernel<<<dim3(S, NH), 256, 0, stream>>>(scp, P, full ? 0 : 1);
    gemm_nt<u16, 0><<<dim3(2, 8, NH), 256, 0, stream>>>(
        P, S, (long)S * S, vt, S, 0, o, NH * HD, HD, S, 1.0f, full ? 2 : 1, -1, 1);
    gemm_nt<float, 0><<<dim3(5, 8, 2), 256, 0, stream>>>(
        o, NH * HD, 0, woTl, NH * HD, 0, t1, H, (long)S * H, NH * HD, 1.0f, 3, -1, 2);
    fused_add_norm<<<S, 256, 0, stream>>>(h, t1, 2, ln2 + l * H, ln3 + l * H, x);

    gemm_nt<u16, 1><<<dim3(32, 8, 1), 256, 0, stream>>>(
        x, H, 0, wguTl, H, 0, mg, I, 0, H, 1.0f, 0, -1, 1);
    gemm_nt<float, 0><<<dim3(5, 8, 4), 256, 0, stream>>>(
        mg, I, 0, wdTl, I, 0, t1, H, (long)S * H, I, 1.0f, 3, -1, 4);
    fused_add_norm<<<S, 256, 0, stream>>>(h, t1, 4, ln4 + l * H,
                                          (l == 17) ? nw : ln1 + (l + 1) * H,
                                          (l == 17) ? hn : x);
  }

  gemm_nt<float, 0><<<dim3(V / 128, 8, 1), 256, 0, stream>>>(
      hn, H, 0, embT, H, 0, out, V, 0, H, 1.0f, 0, -1, 1);
}

// Round 8
// 2186.690 us; speedup vs baseline: 1.2101x; 1.0064x over previous
//
#include <hip/hip_runtime.h>

// Gemma3 forward, MI355X. Round 8: no weight-transpose pass — GEMM B-operand
// staged directly from fp32 weights ([K,N] reg-transpose or [N,K] reg-convert),
// logits reads embed fp32 directly, QKV split-K=2. Attention path unchanged.
// L=18 H=640 NH=4 NKV=1 HD=256 I=2048 V=32768 B=1 S=1024 WINDOW=512

typedef unsigned short u16;
typedef __attribute__((ext_vector_type(4))) float f32x4;
typedef __attribute__((ext_vector_type(8))) short bf16x8;

#define DEV static __device__ __forceinline__
#define BIGN (1 << 30)

DEV u16 f2bf(float f) {  // round-to-nearest-even fp32 -> bf16
  union { float f; unsigned u; } x; x.f = f;
  unsigned r = x.u + 0x7fffu + ((x.u >> 16) & 1u);
  return (u16)(r >> 16);
}

#define GLOAD16(gp, lp) __builtin_amdgcn_global_load_lds( \
    (const __attribute__((address_space(1))) void*)(gp), \
    (__attribute__((address_space(3))) void*)(lp), 16, 0, 0)

DEV float blockSum(float v, float* red) {
#pragma unroll
  for (int o = 32; o; o >>= 1) v += __shfl_down(v, o);
  int lane = threadIdx.x & 63, wid = threadIdx.x >> 6;
  if (lane == 0) red[wid] = v;
  __syncthreads();
  float s = red[0] + red[1] + red[2] + red[3];
  __syncthreads();
  return s;
}

DEV float blockMax(float v, float* red) {
#pragma unroll
  for (int o = 32; o; o >>= 1) v = fmaxf(v, __shfl_down(v, o));
  int lane = threadIdx.x & 63, wid = threadIdx.x >> 6;
  if (lane == 0) red[wid] = v;
  __syncthreads();
  float s = fmaxf(fmaxf(red[0], red[1]), fmaxf(red[2], red[3]));
  __syncthreads();
  return s;
}

DEV void cstore(float* C, size_t i, float v) { C[i] = v; }
DEV void cstore(u16* C, size_t i, float v) { C[i] = f2bf(v); }

// ---- GEMM NT: C[M,N] = alpha * A[M,K]bf16 * B^T ----
// 128x128 tile, BK=64, double-buffered LDS, XOR-swizzled (16B-block ^ row&7).
// A: bf16 [M,K], staged via global_load_lds with depth-1 prefetch.
// BMODE 0: B bf16 [N,K] (K-contig), gload_lds like A.
// BMODE 1: B fp32 [K,N] (weights, N-contig): reg-staged 8k x 4n micro-tiles,
//          convert+transpose in reg, ds_write_b128 into swizzled LDS.
//          Up to 3 source tensors split along N at ns1/ns2 (QKV), or GEGLU
//          g/u interleave-at-16-cols mapping (B0=g, B1=u).
// BMODE 2: B fp32 [N,K] (K-contig, embed): reg-staged convert, same LDS slots.
// nshift: -1 plain; -2 causal tile-skip; >=0 sliding band n0=m0-nshift+bx*128.
// kmode: 0 full K; 1 sliding K-band; 2 causal K-band; 3 split-K over blockIdx.z.
template <typename CT, int GEGLU, int BMODE>
__global__ __launch_bounds__(256) void gemm_nt(
    const u16* __restrict__ A, int lda, long sA,
    const void* __restrict__ B0v, int ldb0,
    const void* __restrict__ B1v, int ldb1,
    const void* __restrict__ B2v, int ldb2,
    int ns1, int ns2,
    CT* __restrict__ C, int ldc, long sC,
    int K, float alpha, int kmode, int nshift, int ksplit) {
  __shared__ __align__(16) u16 As[2 * 128 * 64];
  __shared__ __align__(16) u16 Bs[2 * 128 * 64];
  const int m0 = blockIdx.y * 128;
  int n0;
  if (nshift == -1) n0 = blockIdx.x * 128;
  else if (nshift == -2) { n0 = blockIdx.x * 128; if (n0 > m0) return; }
  else { n0 = m0 - nshift + blockIdx.x * 128; if (n0 < 0) return; }
  int klo = 0, khi = K;
  if (kmode == 1) { klo = m0 - 512; if (klo < 0) klo = 0; khi = m0 + 128; if (khi > K) khi = K; }
  else if (kmode == 2) { khi = m0 + 128; if (khi > K) khi = K; }
  else if (kmode == 3) { int kl = K / ksplit; klo = blockIdx.z * kl; khi = klo + kl; }
  A += (long)blockIdx.z * sA;

  const int t = threadIdx.x;
  const int l = t & 63, w = t >> 6;
  const int wr = w >> 1, wc = w & 1;        // 2x2 waves, each 64x64 out
  const int lr = l & 15, lk = l >> 4;
  const int axr = lr & 7;                   // ds_read swizzle key
  const int srow = t >> 3;                  // staging row 0..31 (+32p)
  const int scolx = ((t & 7) ^ (srow & 7)) << 3;  // pre-swizzled global col
  const u16* Ag = A + (size_t)(m0 + srow) * lda + scolx;
  const int nsteps = (khi - klo) >> 6;

  auto stageA = [&](int db, int k0) {
    u16* al = As + db * 8192 + w * 512;     // wave-uniform LDS base
#pragma unroll
    for (int p = 0; p < 4; ++p)
      GLOAD16(Ag + k0 + (size_t)(32 * p) * lda, al + p * 2048);
  };

  // ---- B staging state ----
  const u16* Bg16 = nullptr;                // mode 0
  const float* Bp = nullptr; int bldb = 0, bcol = 0, krow0 = 0;  // mode 1
  f32x4 fb[8];                              // modes 1/2 reg stage
  if constexpr (BMODE == 0) {
    Bg16 = (const u16*)B0v + (size_t)(n0 + srow) * ldb0 + scolx;
  } else if constexpr (BMODE == 1) {
    int rv = n0 + (l & 31) * 4;             // virtual B^T row (n) of this thread
    if (GEGLU) {
      int half = (rv >> 4) & 1;
      Bp = (const float*)(half ? B1v : B0v);
      bldb = half ? ldb1 : ldb0;
      bcol = (rv >> 5) * 16 + (rv & 15);
    } else if (rv >= ns2) { Bp = (const float*)B2v; bldb = ldb2; bcol = rv - ns2; }
    else if (rv >= ns1)   { Bp = (const float*)B1v; bldb = ldb1; bcol = rv - ns1; }
    else                  { Bp = (const float*)B0v; bldb = ldb0; bcol = rv; }
    krow0 = w * 16 + (l >> 5) * 8;          // 8 consecutive k rows per thread
  } else {
    Bp = (const float*)B0v;                 // [N, K] fp32, ldb0 = K
  }

  auto stageB0 = [&](int db, int k0) {      // mode 0: gload_lds
    u16* bl = Bs + db * 8192 + w * 512;
#pragma unroll
    for (int p = 0; p < 4; ++p)
      GLOAD16(Bg16 + k0 + (size_t)(32 * p) * ldb0, bl + p * 2048);
  };
  auto loadB = [&](int k0) {                // modes 1/2: global -> regs
    if constexpr (BMODE == 1) {
#pragma unroll
      for (int j = 0; j < 8; ++j)
        fb[j] = *(const f32x4*)&Bp[(size_t)(k0 + krow0 + j) * bldb + bcol];
    } else if constexpr (BMODE == 2) {
#pragma unroll
      for (int p = 0; p < 4; ++p)
#pragma unroll
        for (int q = 0; q < 2; ++q)
          fb[p * 2 + q] = *(const f32x4*)&Bp[(size_t)(n0 + srow + 32 * p) * ldb0 +
                                             k0 + (((t & 7) ^ (srow & 7)) << 3) + q * 4];
    }
  };
  auto writeB = [&](int db) {               // modes 1/2: regs -> swizzled LDS
    if constexpr (BMODE == 1) {
      int kb = w * 2 + (l >> 5);            // 16B k-block index 0..7
#pragma unroll
      for (int e = 0; e < 4; ++e) {
        int row = (l & 31) * 4 + e;
        u16 tmp[8];
#pragma unroll
        for (int j = 0; j < 8; ++j) tmp[j] = f2bf(fb[j][e]);
        *(int4*)&Bs[db * 8192 + row * 64 + ((kb ^ (row & 7)) << 3)] = *(int4*)tmp;
      }
    } else if constexpr (BMODE == 2) {
#pragma unroll
      for (int p = 0; p < 4; ++p) {
        u16 tmp[8];
#pragma unroll
        for (int j = 0; j < 8; ++j) tmp[j] = f2bf(fb[p * 2 + j / 4][j & 3]);
        *(int4*)&Bs[db * 8192 + (srow + 32 * p) * 64 + ((t & 7) << 3)] = *(int4*)tmp;
      }
    }
  };

  f32x4 acc[4][4] = {};
  auto compute = [&](int db) {
    const u16* Ab = As + db * 8192;
    const u16* Bb = Bs + db * 8192;
    bf16x8 af[2][4], bfr[2][4];
#pragma unroll
    for (int kk = 0; kk < 2; ++kk)
#pragma unroll
      for (int i = 0; i < 4; ++i) {
        af[kk][i]  = *(const bf16x8*)&Ab[(wr * 64 + i * 16 + lr) * 64 + (((kk * 4 + lk) ^ axr) << 3)];
        bfr[kk][i] = *(const bf16x8*)&Bb[(wc * 64 + i * 16 + lr) * 64 + (((kk * 4 + lk) ^ axr) << 3)];
      }
#pragma unroll
    for (int kk = 0; kk < 2; ++kk)
#pragma unroll
      for (int mi = 0; mi < 4; ++mi)
#pragma unroll
        for (int ni = 0; ni < 4; ++ni)
          acc[mi][ni] = __builtin_amdgcn_mfma_f32_16x16x32_bf16(af[kk][mi], bfr[kk][ni], acc[mi][ni], 0, 0, 0);
  };

  if constexpr (BMODE == 0) {
    stageA(0, klo); stageB0(0, klo);
    for (int s = 0; s < nsteps; ++s) {
      __syncthreads();                      // drains prefetch; joins prior ds_reads
      const int db = s & 1;
      if (s + 1 < nsteps) { stageA(db ^ 1, klo + (s + 1) * 64); stageB0(db ^ 1, klo + (s + 1) * 64); }
      compute(db);
    }
  } else {
    loadB(klo); stageA(0, klo);
    for (int s = 0; s < nsteps; ++s) {
      const int db = s & 1;
      writeB(db);                           // B tile s (regs loaded last iter)
      if (s + 1 < nsteps) loadB(klo + (s + 1) * 64);
      __syncthreads();                      // drains A gload(s) + B writes visible
      if (s + 1 < nsteps) stageA(db ^ 1, klo + (s + 1) * 64);
      compute(db);
    }
  }

  C += (long)blockIdx.z * sC;
  if (GEGLU) {
    // acc[ni]: virtual B rows n0+wc*64+ni*16+lr; (r&31)<16 are g, >=16 are u.
#pragma unroll
    for (int mi = 0; mi < 4; ++mi) {
      int row = m0 + wr * 64 + mi * 16 + lk * 4;
#pragma unroll
      for (int np = 0; np < 2; ++np) {
        int col = (n0 + wc * 64) / 2 + np * 16 + lr;
#pragma unroll
        for (int j = 0; j < 4; ++j) {
          float g = acc[mi][2 * np][j], u = acc[mi][2 * np + 1][j];
          float z = 0.7978845608028654f * (g + 0.044715f * g * g * g);
          float th = 2.0f / (1.0f + __expf(-2.0f * z)) - 1.0f;
          cstore(C, (size_t)(row + j) * ldc + col, 0.5f * g * (1.0f + th) * u);
        }
      }
    }
  } else {
#pragma unroll
    for (int mi = 0; mi < 4; ++mi) {
      int row = m0 + wr * 64 + mi * 16 + lk * 4;
#pragma unroll
      for (int ni = 0; ni < 4; ++ni) {
        int col = n0 + wc * 64 + ni * 16 + lr;
#pragma unroll
        for (int j = 0; j < 4; ++j)
          cstore(C, (size_t)(row + j) * ldc + col, acc[mi][ni][j] * alpha);
      }
    }
  }
}

// ---- small kernels ----
// h = embed[ids[s]] * sqrt(H); x = bf16(rms(h, ln1))
__global__ void gather_rms_kernel(const int* __restrict__ ids, const float* __restrict__ embed,
                                  const float* __restrict__ w, float* __restrict__ h,
                                  u16* __restrict__ x) {
  __shared__ float red[8];
  const int s = blockIdx.x, t = threadIdx.x;
  const float* src = embed + (size_t)ids[s] * 640;
  const float scale = sqrtf(640.0f);
  float hv[3];
  float ss = 0.0f;
#pragma unroll
  for (int i = 0; i < 3; ++i) {
    int c = t + i * 256;
    float v = (c < 640) ? src[c] * scale : 0.0f;
    hv[i] = v; ss += v * v;
  }
  ss = blockSum(ss, red);
  const float sc = rsqrtf(ss * (1.0f / 640.0f) + 1e-6f);
#pragma unroll
  for (int i = 0; i < 3; ++i) {
    int c = t + i * 256;
    if (c < 640) {
      h[(size_t)s * 640 + c] = hv[i];
      x[(size_t)s * 640 + c] = f2bf(hv[i] * sc * (1.0f + w[c]));
    }
  }
}

// h += rms(sum_z t1[z], wa); xout = bf16(rms(h, wn))
__global__ void fused_add_norm(float* __restrict__ h, const float* __restrict__ t1,
                               int nsl, const float* __restrict__ wa,
                               const float* __restrict__ wn, u16* __restrict__ xout) {
  __shared__ float red[8];
  const int row = blockIdx.x, t = threadIdx.x;
  float ts[3], hv[3];
  float ss = 0.0f;
#pragma unroll
  for (int i = 0; i < 3; ++i) {
    int c = t + i * 256;
    float v = 0.0f;
    if (c < 640) {
      v = t1[(size_t)row * 640 + c];
      for (int z = 1; z < nsl; ++z) v += t1[(size_t)z * 655360 + (size_t)row * 640 + c];
    }
    ts[i] = v; ss += v * v;
  }
  ss = blockSum(ss, red);
  const float s1 = rsqrtf(ss * (1.0f / 640.0f) + 1e-6f);
  float ss2 = 0.0f;
#pragma unroll
  for (int i = 0; i < 3; ++i) {
    int c = t + i * 256;
    float v = 0.0f;
    if (c < 640) v = h[(size_t)row * 640 + c] + ts[i] * s1 * (1.0f + wa[c]);
    hv[i] = v; ss2 += v * v;
  }
  ss2 = blockSum(ss2, red);
  const float s2 = rsqrtf(ss2 * (1.0f / 640.0f) + 1e-6f);
#pragma unroll
  for (int i = 0; i < 3; ++i) {
    int c = t + i * 256;
    if (c < 640) {
      h[(size_t)row * 640 + c] = hv[i];
      xout[(size_t)row * 640 + c] = f2bf(hv[i] * s2 * (1.0f + wn[c]));
    }
  }
}

__global__ void rope_tables_kernel(float* cg, float* sg, float* cl, float* sl) {
  int s = blockIdx.x, t = threadIdx.x;  // t < 128
  float e = -(float)t * (1.0f / 128.0f);
  float ag = (float)s * expf(e * logf(1000000.0f));
  float al = (float)s * expf(e * logf(10000.0f));
  cg[s * 128 + t] = cosf(ag); sg[s * 128 + t] = sinf(ag);
  cl[s * 128 + t] = cosf(al); sl[s * 128 + t] = sinf(al);
}

// per (s, unit): unit 0..3 Q heads (rms+rope), 4 K (rms+rope), 5 V transpose.
// qkvf has 2 split-K slices (stride S*1536) summed here.
__global__ void rope_fused(const float* __restrict__ qkvf, const float* __restrict__ qn,
                           const float* __restrict__ kn, u16* __restrict__ qb,
                           u16* __restrict__ kb, u16* __restrict__ vt,
                           const float* __restrict__ ct, const float* __restrict__ st) {
  __shared__ float red[8];
  __shared__ float sh[256];
  const int s = blockIdx.x, hh = blockIdx.y, t = threadIdx.x;
  const long SL = (long)1024 * 1536;
  if (hh == 5) {
    long i = (size_t)s * 1536 + 1280 + t;
    vt[(size_t)t * 1024 + s] = f2bf(qkvf[i] + qkvf[i + SL]);
    return;
  }
  long i = (size_t)s * 1536 + hh * 256 + t;  // hh==4 -> K at 1024
  const float* nw = (hh == 4) ? kn : qn;
  float x = qkvf[i] + qkvf[i + SL];
  float ss = blockSum(x * x, red);
  float n = x * rsqrtf(ss * (1.0f / 256.0f) + 1e-6f) * (1.0f + nw[t]);
  sh[t] = n;
  __syncthreads();
  float cosv = ct[s * 128 + (t & 127)];
  float sinv = st[s * 128 + (t & 127)];
  float partner = (t < 128) ? -sh[t + 128] : sh[t - 128];
  u16 r = f2bf(n * cosv + partner * sinv);
  if (hh == 4) kb[(size_t)s * 256 + t] = r;
  else qb[((size_t)hh * 1024 + s) * 256 + t] = r;
}

// masked softmax; writes P over exactly the band PV reads. mode 1 sliding, 0 causal
__global__ void softmax_kernel(const float* __restrict__ sc, u16* __restrict__ P, int mode) {
  __shared__ float red[8];
  const int i = blockIdx.x, hh = blockIdx.y, t = threadIdx.x;
  const float* row = sc + ((size_t)hh * 1024 + i) * 1024;
  u16* prow = P + ((size_t)hh * 1024 + i) * 1024;
  const int m0 = i & ~127;
  int lo = 0, wlo = 0;
  if (mode) {
    lo = i - 511; if (lo < 0) lo = 0;
    wlo = m0 - 512; if (wlo < 0) wlo = 0;
  }
  const int whi = m0 + 127;
  float m = -1e30f;
  for (int j = lo + t; j <= i; j += 256) m = fmaxf(m, row[j]);
  m = blockMax(m, red);
  float sum = 0.0f;
  for (int j = lo + t; j <= i; j += 256) sum += __expf(row[j] - m);
  sum = blockSum(sum, red);
  float inv = 1.0f / sum;
  for (int j = wlo + t; j <= whi; j += 256) {
    float v = (j >= lo && j <= i) ? __expf(row[j] - m) * inv : 0.0f;
    prow[j] = f2bf(v);
  }
}

extern "C" void kernel_launch(void* const* d_in, const int* in_sizes, int n_in,
                              void* d_out, int out_size, void* d_ws, size_t ws_size,
                              hipStream_t stream) {
  (void)in_sizes; (void)n_in; (void)out_size; (void)ws_size;
  const int*   ids   = (const int*)d_in[0];
  // d_in[1] = is_full; deterministic (l+1)%6==0, hardcoded.
  const float* embed = (const float*)d_in[2];
  const float* wq    = (const float*)d_in[3];
  const float* wk    = (const float*)d_in[4];
  const float* wv    = (const float*)d_in[5];
  const float* wo    = (const float*)d_in[6];
  const float* qn    = (const float*)d_in[7];
  const float* kn    = (const float*)d_in[8];
  const float* ln1   = (const float*)d_in[9];
  const float* ln2   = (const float*)d_in[10];
  const float* ln3   = (const float*)d_in[11];
  const float* ln4   = (const float*)d_in[12];
  const float* wg    = (const float*)d_in[13];
  const float* wu    = (const float*)d_in[14];
  const float* wd    = (const float*)d_in[15];
  const float* nw    = (const float*)d_in[16];
  float* out = (float*)d_out;

  const int S = 1024, H = 640, NH = 4, HD = 256, I = 2048, V = 32768;

  unsigned char* p = (unsigned char*)d_ws;
  auto alloc = [&](size_t b) { void* r = (void*)p; p += (b + 255) & ~(size_t)255; return r; };
  float* h     = (float*)alloc((size_t)S * H * 4);
  u16*   x     = (u16*)alloc((size_t)S * H * 2);
  float* qkvf  = (float*)alloc((size_t)2 * S * 1536 * 4);  // 2 split-K slices
  u16*   qb    = (u16*)alloc((size_t)NH * S * HD * 2);
  u16*   kb    = (u16*)alloc((size_t)S * HD * 2);
  u16*   vt    = (u16*)alloc((size_t)HD * S * 2);
  float* scp   = (float*)alloc((size_t)NH * S * S * 4);
  u16*   P     = (u16*)alloc((size_t)NH * S * S * 2);
  u16*   o     = (u16*)alloc((size_t)S * NH * HD * 2);
  float* t1    = (float*)alloc((size_t)4 * S * H * 4);     // up to 4 split-K slices
  u16*   mg    = (u16*)alloc((size_t)S * I * 2);
  u16*   hn    = (u16*)alloc((size_t)S * H * 2);
  float* cg    = (float*)alloc((size_t)S * 128 * 4);
  float* sg    = (float*)alloc((size_t)S * 128 * 4);
  float* cl    = (float*)alloc((size_t)S * 128 * 4);
  float* sl2   = (float*)alloc((size_t)S * 128 * 4);

  rope_tables_kernel<<<S, 128, 0, stream>>>(cg, sg, cl, sl2);
  gather_rms_kernel<<<S, 256, 0, stream>>>(ids, embed, ln1, h, x);

  for (int l = 0; l < 18; ++l) {
    bool full = ((l + 1) % 6) == 0;
    const float* wq_l = wq + (size_t)l * H * 1024;
    const float* wk_l = wk + (size_t)l * H * 256;
    const float* wv_l = wv + (size_t)l * H * 256;
    const float* wo_l = wo + (size_t)l * 1024 * H;
    const float* wg_l = wg + (size_t)l * H * I;
    const float* wu_l = wu + (size_t)l * H * I;
    const float* wd_l = wd + (size_t)l * I * H;

    // QKV: N=1536 from {wq[640,1024], wk[640,256], wv[640,256]}, split-K=2
    gemm_nt<float, 0, 1><<<dim3(12, 8, 2), 256, 0, stream>>>(
        x, H, 0, wq_l, 1024, wk_l, 256, wv_l, 256, 1024, 1280,
        qkvf, 1536, (long)S * 1536, H, 1.0f, 3, -1, 2);
    rope_fused<<<dim3(S, 6), 256, 0, stream>>>(qkvf, qn + l * HD, kn + l * HD, qb, kb, vt,
                                               full ? cg : cl, full ? sg : sl2);
    if (full)
      gemm_nt<float, 0, 0><<<dim3(8, 8, NH), 256, 0, stream>>>(
          qb, HD, (long)S * HD, kb, HD, nullptr, 0, nullptr, 0, BIGN, BIGN,
          scp, S, (long)S * S, HD, 0.0625f, 0, -2, 1);
    else
      gemm_nt<float, 0, 0><<<dim3(5, 8, NH), 256, 0, stream>>>(
          qb, HD, (long)S * HD, kb, HD, nullptr, 0, nullptr, 0, BIGN, BIGN,
          scp, S, (long)S * S, HD, 0.0625f, 0, 512, 1);
    softmax_kernel<<<dim3(S, NH), 256, 0, stream>>>(scp, P, full ? 0 : 1);
    gemm_nt<u16, 0, 0><<<dim3(2, 8, NH), 256, 0, stream>>>(
        P, S, (long)S * S, vt, S, nullptr, 0, nullptr, 0, BIGN, BIGN,
        o, NH * HD, HD, S, 1.0f, full ? 2 : 1, -1, 1);
    gemm_nt<float, 0, 1><<<dim3(5, 8, 2), 256, 0, stream>>>(
        o, NH * HD, 0, wo_l, 640, nullptr, 0, nullptr, 0, BIGN, BIGN,
        t1, H, (long)S * H, NH * HD, 1.0f, 3, -1, 2);
    fused_add_norm<<<S, 256, 0, stream>>>(h, t1, 2, ln2 + l * H, ln3 + l * H, x);

    // gate+up N=4096 virtual (g/u 16-col interleave), GEGLU epilogue
    gemm_nt<u16, 1, 1><<<dim3(32, 8, 1), 256, 0, stream>>>(
        x, H, 0, wg_l, 2048, wu_l, 2048, nullptr, 0, BIGN, BIGN,
        mg, I, 0, H, 1.0f, 0, -1, 1);
    gemm_nt<float, 0, 1><<<dim3(5, 8, 4), 256, 0, stream>>>(
        mg, I, 0, wd_l, 640, nullptr, 0, nullptr, 0, BIGN, BIGN,
        t1, H, (long)S * H, I, 1.0f, 3, -1, 4);
    fused_add_norm<<<S, 256, 0, stream>>>(h, t1, 4, ln4 + l * H,
                                          (l == 17) ? nw : ln1 + (l + 1) * H,
                                          (l == 17) ? hn : x);
  }

  // logits = hn @ embed^T, B = embed fp32 [V, H] K-contiguous (mode 2)
  gemm_nt<float, 0, 2><<<dim3(V / 128, 8, 1), 256, 0, stream>>>(
      hn, H, 0, embed, H, nullptr, 0, nullptr, 0, BIGN, BIGN,
      out, V, 0, H, 1.0f, 0, -1, 1);
}